// Round 10
// baseline (82.602 us; speedup 1.0000x reference)
//
#include <hip/hip_runtime.h>
#include <hip/hip_bf16.h>

#define NH 16
#define DH 64
#define LL 2048
#define DM 1024
#define SCALE2 0.1803368801111204f   /* 0.125 * log2(e) */
#define GUARD_HI 60.0f               /* overflow guard (~40 sigma) */
#define NT2 (LL / 128)

typedef __attribute__((ext_vector_type(4))) float f32x4;
typedef __attribute__((ext_vector_type(16))) float f32x16;
typedef __attribute__((ext_vector_type(8))) short bf16x8;

__device__ __forceinline__ unsigned pk2(float lo, float hi) {
    __hip_bfloat162 h = __float22bfloat162_rn(make_float2(lo, hi));
    union { __hip_bfloat162 h; unsigned u; } c; c.h = h; return c.u;
}
__device__ __forceinline__ bf16x8 cvt8(float4 a, float4 b) {
    union { bf16x8 v; unsigned u[4]; } r;
    r.u[0] = pk2(a.x, a.y); r.u[1] = pk2(a.z, a.w);
    r.u[2] = pk2(b.x, b.y); r.u[3] = pk2(b.z, b.w);
    return r.v;
}
__device__ __forceinline__ float exp2_fast(float x) {
    float y;
    asm("v_exp_f32 %0, %1" : "=v"(y) : "v"(x));
    return y;
}
// keep-bit apply: nw bit idx == 1 -> keep p, else 0 (idx compile-time)
__device__ __forceinline__ float keepf(float p, unsigned nw, int idx) {
    int k = (int)(nw << (31 - idx)) >> 31;
    unsigned pu = __builtin_bit_cast(unsigned, p) & (unsigned)k;
    return __builtin_bit_cast(float, pu);
}

// ---- mask pre-pack v4: per-(q, kb) keep-words ----
// bits[((b*16 + t)*2048 + q)*4 + kb] bit (8*blk + 4*h + r) =
//     !mask[b][q][ t*128 + kb*32 + 8*blk + 4*h + r ]
__global__ __launch_bounds__(256) void pack_mask4(const void* __restrict__ mask,
                                                  unsigned* __restrict__ bits)
{
    const int tid = threadIdx.x;
    const int lane = tid & 63;
    const int* mw = (const int*)mask;
    unsigned long long bad = __ballot((unsigned)mw[lane] > 1u);
    const bool is_int = (bad == 0ULL);

    const int wid = blockIdx.x * 256 + tid;   // 0 .. 2*16*2048*4-1
    const int kb = wid & 3;
    const int q = (wid >> 2) & 2047;
    const int t = (wid >> 13) & 15;
    const int b = wid >> 17;
    unsigned m = 0;
    if (is_int) {
        const int* p = (const int*)mask + ((size_t)b * 2048 + q) * 2048
                     + t * 128 + kb * 32;
        #pragma unroll
        for (int h = 0; h < 2; ++h)
            #pragma unroll
            for (int blk = 0; blk < 4; ++blk) {
                int4 v = *(const int4*)(p + 8 * blk + 4 * h);
                int base = 8 * blk + 4 * h;
                m |= (v.x ? 1u : 0u) << base;
                m |= (v.y ? 1u : 0u) << (base + 1);
                m |= (v.z ? 1u : 0u) << (base + 2);
                m |= (v.w ? 1u : 0u) << (base + 3);
            }
    } else {
        const unsigned char* pb = (const unsigned char*)mask
                                + ((size_t)b * 2048 + q) * 2048 + t * 128 + kb * 32;
        #pragma unroll
        for (int h = 0; h < 2; ++h)
            #pragma unroll
            for (int blk = 0; blk < 4; ++blk) {
                unsigned v = *(const unsigned*)(pb + 8 * blk + 4 * h);
                int base = 8 * blk + 4 * h;
                m |= (v & 1u) << base;
                m |= ((v >> 8) & 1u) << (base + 1);
                m |= ((v >> 16) & 1u) << (base + 2);
                m |= ((v >> 24) & 1u) << (base + 3);
            }
    }
    bits[wid] = ~m;   // inverted: 1 = keep
}

// ---- K pre-convert (unchanged image): f32 -> bf16, 8KB per (b,h,ktile) ----
// logical (key 0..63, col 0..63) -> tile[key*64 + ((col>>3)^(key&7))*8 + (col&7)]
__global__ __launch_bounds__(256) void prep_k(const float* __restrict__ K,
                                              short* __restrict__ Kb)
{
    const int kt = blockIdx.x, h = blockIdx.y, b = blockIdx.z;
    const int tid = threadIdx.x;
    const int key = tid >> 2;
    const int c8 = (tid & 3) * 2;
    const float* src = K + ((size_t)b * LL + kt * 64 + key) * DM + h * DH + c8 * 8;
    float4 a = *(const float4*)(src);
    float4 bb = *(const float4*)(src + 4);
    float4 c = *(const float4*)(src + 8);
    float4 d = *(const float4*)(src + 12);
    short* dst = Kb + (((size_t)(b * NH + h) * 32 + kt) << 12);
    *(bf16x8*)&dst[key * 64 + ((c8 ^ (key & 7)) << 3)] = cvt8(a, bb);
    *(bf16x8*)&dst[key * 64 + (((c8 + 1) ^ (key & 7)) << 3)] = cvt8(c, d);
}

// ---- V pre-convert v3: sigma-permuted V^T image for 32x32 PV ----
// key = 16*kg + w16; half = (w16>>2)&1; i = (w16&3) + 4*(w16>>3); sg = kg*2+half
// tile[dv*64 + ((sg ^ (dv&7))<<3) + i]  ->  b128 read at sg = 2*m + h gives
// slot i holding V^T[dv][16m + 4h + (i&3) + 8*(i>>2)]  (= sigma(h,i))
__global__ __launch_bounds__(256) void prep_v(const float* __restrict__ V,
                                              short* __restrict__ Vb)
{
    const int kt = blockIdx.x, h = blockIdx.y, b = blockIdx.z;
    const int tid = threadIdx.x;
    const int kp = tid & 31;              // keys 2kp, 2kp+1
    const int dv8 = tid >> 5;
    const float* s0 = V + ((size_t)b * LL + kt * 64 + 2 * kp) * DM + h * DH + dv8 * 8;
    float4 a0 = *(const float4*)(s0);
    float4 a1 = *(const float4*)(s0 + 4);
    float4 b0 = *(const float4*)(s0 + DM);
    float4 b1 = *(const float4*)(s0 + DM + 4);
    float av[8] = {a0.x, a0.y, a0.z, a0.w, a1.x, a1.y, a1.z, a1.w};
    float bv[8] = {b0.x, b0.y, b0.z, b0.w, b1.x, b1.y, b1.z, b1.w};
    short* dst = Vb + (((size_t)(b * NH + h) * 32 + kt) << 12);
    const int w16 = (2 * kp) & 15;        // even
    const int kg = kp >> 3;
    const int half = (w16 >> 2) & 1;
    const int i0 = (w16 & 3) + 4 * (w16 >> 3);
    const int sg = kg * 2 + half;
    #pragma unroll
    for (int j = 0; j < 8; ++j) {
        int dv = dv8 * 8 + j;
        int off = dv * 64 + ((sg ^ (dv & 7)) << 3) + i0;
        *(unsigned*)&dst[off] = pk2(av[j], bv[j]);
    }
}

// ---- main v3: 256 threads (4 waves x 32 q), 32x32 MFMA, 128 keys/iter ----
__global__ __launch_bounds__(256, 2) void mha_fwd3(
    const float* __restrict__ Q, const short* __restrict__ Kb,
    const short* __restrict__ Vb, const unsigned* __restrict__ mbits,
    float* __restrict__ out)
{
    const int bid = blockIdx.x;           // 512 blocks
    const int xcd = bid & 7;
    const int j = bid >> 3;               // 0..63
    const int pair = xcd * 4 + (j >> 4);  // 0..31
    const int qblk = j & 15;
    const int hd = pair & 15;
    const int b = pair >> 4;

    const int tid = threadIdx.x;
    const int w = tid >> 6;               // wave 0..3
    const int lane = tid & 63;
    const int lq = lane & 31;             // q within wave strip (col of S^T)
    const int hh = lane >> 5;             // lane half

    const int qbase = qblk * 128 + w * 32;

    __shared__ short Kt[2][2][4096];
    __shared__ short Vt[2][2][4096];

    const short* Ktile0 = Kb + ((size_t)(b * NH + hd) << 17);
    const short* Vtile0 = Vb + ((size_t)(b * NH + hd) << 17);
    const unsigned* Mp = mbits + (size_t)b * (16 * 8192) + (qbase + lq) * 4;

    // prologue: mask(0) FIRST (stays oldest in vm queue), then 8 gloads of t=0
    uint4 mreg = *(const uint4*)(Mp);
    #pragma unroll
    for (int sub = 0; sub < 2; ++sub)
        #pragma unroll
        for (int i = 0; i < 2; ++i) {
            __builtin_amdgcn_global_load_lds(
                (const unsigned*)(Ktile0 + sub * 4096 + w * 1024 + i * 512 + lane * 8),
                (unsigned*)&Kt[0][sub][w * 1024 + i * 512 + lane * 8], 16, 0, 0);
            __builtin_amdgcn_global_load_lds(
                (const unsigned*)(Vtile0 + sub * 4096 + w * 1024 + i * 512 + lane * 8),
                (unsigned*)&Vt[0][sub][w * 1024 + i * 512 + lane * 8], 16, 0, 0);
        }

    // Q fragments (B-operand of 32x32x16): qf[d16] slot i -> SCALE2*Q[q][16*d16+8*hh+i]
    bf16x8 qf[4];
    {
        const float* qp = Q + ((size_t)b * LL + qbase + lq) * DM + hd * DH + 8 * hh;
        #pragma unroll
        for (int d16 = 0; d16 < 4; ++d16) {
            float4 a = *(const float4*)(qp + 16 * d16);
            float4 c = *(const float4*)(qp + 16 * d16 + 4);
            a.x *= SCALE2; a.y *= SCALE2; a.z *= SCALE2; a.w *= SCALE2;
            c.x *= SCALE2; c.y *= SCALE2; c.z *= SCALE2; c.w *= SCALE2;
            qf[d16] = cvt8(a, c);
        }
    }

    f32x16 o0, o1;
    #pragma unroll
    for (int i = 0; i < 16; ++i) { o0[i] = 0.f; o1[i] = 0.f; }
    float l_own = 0.f;
    float m_shift = 0.f;
    const int sh4 = 4 * hh;

    asm volatile("s_waitcnt vmcnt(0)" ::: "memory");
    __builtin_amdgcn_s_barrier();

    #pragma unroll 2
    for (int t = 0; t < NT2; ++t) {
        const int cur = t & 1;
        const uint4 m4 = mreg;
        if (t + 1 < NT2) {
            mreg = *(const uint4*)(Mp + (size_t)(t + 1) * 8192);
            const short* kb_ = Ktile0 + (size_t)(t + 1) * 8192;
            const short* vb_ = Vtile0 + (size_t)(t + 1) * 8192;
            #pragma unroll
            for (int sub = 0; sub < 2; ++sub)
                #pragma unroll
                for (int i = 0; i < 2; ++i) {
                    __builtin_amdgcn_global_load_lds(
                        (const unsigned*)(kb_ + sub * 4096 + w * 1024 + i * 512 + lane * 8),
                        (unsigned*)&Kt[cur ^ 1][sub][w * 1024 + i * 512 + lane * 8], 16, 0, 0);
                    __builtin_amdgcn_global_load_lds(
                        (const unsigned*)(vb_ + sub * 4096 + w * 1024 + i * 512 + lane * 8),
                        (unsigned*)&Vt[cur ^ 1][sub][w * 1024 + i * 512 + lane * 8], 16, 0, 0);
                }
            // in flight: 8 gl(t) + mask(t+1) + 8 gl(t+1) -> drain gl(t) only
            asm volatile("s_waitcnt vmcnt(9)" ::: "memory");
        } else {
            asm volatile("s_waitcnt vmcnt(0)" ::: "memory");
        }
        __builtin_amdgcn_s_barrier();
        __builtin_amdgcn_sched_barrier(0);

        // ---- QK: 16 mfma_32x32x16, S^T[key][q], col=q=lane&31 ----
        f32x16 s[4];
        __builtin_amdgcn_s_setprio(1);
        #pragma unroll
        for (int kb2 = 0; kb2 < 4; ++kb2) {
            const int sub = kb2 >> 1;
            const int keyrow = (kb2 & 1) * 32 + lq;
            const int swz = keyrow & 7;
            f32x16 acc;
            #pragma unroll
            for (int i = 0; i < 16; ++i) acc[i] = 0.f;
            #pragma unroll
            for (int d16 = 0; d16 < 4; ++d16) {
                bf16x8 kf = *(const bf16x8*)
                    &Kt[cur][sub][keyrow * 64 + (((2 * d16 + hh) ^ swz) << 3)];
                acc = __builtin_amdgcn_mfma_f32_32x32x16_bf16(kf, qf[d16], acc, 0, 0, 0);
            }
            s[kb2] = acc;
        }
        __builtin_amdgcn_s_setprio(0);

        // ---- overflow guard (rarely taken) ----
        float mx = -1e30f;
        #pragma unroll
        for (int kb2 = 0; kb2 < 4; ++kb2) {
            float a0 = fmaxf(fmaxf(s[kb2][0], s[kb2][1]), fmaxf(s[kb2][2], s[kb2][3]));
            float a1 = fmaxf(fmaxf(s[kb2][4], s[kb2][5]), fmaxf(s[kb2][6], s[kb2][7]));
            float a2 = fmaxf(fmaxf(s[kb2][8], s[kb2][9]), fmaxf(s[kb2][10], s[kb2][11]));
            float a3 = fmaxf(fmaxf(s[kb2][12], s[kb2][13]), fmaxf(s[kb2][14], s[kb2][15]));
            mx = fmaxf(mx, fmaxf(fmaxf(a0, a1), fmaxf(a2, a3)));
        }
        if (__builtin_expect(m_shift != 0.0f, 0)) {
            #pragma unroll
            for (int kb2 = 0; kb2 < 4; ++kb2)
                #pragma unroll
                for (int r = 0; r < 16; ++r) s[kb2][r] -= m_shift;
            mx -= m_shift;
        }
        if (!__all(mx <= GUARD_HI)) {
            float tmax = fmaxf(mx, __shfl_xor(mx, 32, 64));
            float shift = tmax - 30.0f;
            m_shift += shift;
            float alpha = exp2_fast(-shift);
            #pragma unroll
            for (int i = 0; i < 16; ++i) { o0[i] *= alpha; o1[i] *= alpha; }
            l_own *= alpha;
            #pragma unroll
            for (int kb2 = 0; kb2 < 4; ++kb2)
                #pragma unroll
                for (int r = 0; r < 16; ++r) s[kb2][r] -= shift;
        }

        // ---- exp + mask + pack (all in-lane; sigma baked into V image) ----
        unsigned nws0 = m4.x >> sh4, nws1 = m4.y >> sh4;
        unsigned nws2 = m4.z >> sh4, nws3 = m4.w >> sh4;
        unsigned nws[4] = {nws0, nws1, nws2, nws3};
        bf16x8 pfr[4][2];
        float lsum = 0.f;
        #pragma unroll
        for (int kb2 = 0; kb2 < 4; ++kb2) {
            float p[16];
            #pragma unroll
            for (int r = 0; r < 16; ++r)
                p[r] = keepf(exp2_fast(s[kb2][r]), nws[kb2], 8 * (r >> 2) + (r & 3));
            float q1[8];
            #pragma unroll
            for (int i = 0; i < 8; ++i) q1[i] = p[2 * i] + p[2 * i + 1];
            lsum += ((q1[0] + q1[1]) + (q1[2] + q1[3]))
                  + ((q1[4] + q1[5]) + (q1[6] + q1[7]));
            union { bf16x8 v; unsigned u[4]; } pa, pb;
            pa.u[0] = pk2(p[0], p[1]);  pa.u[1] = pk2(p[2], p[3]);
            pa.u[2] = pk2(p[4], p[5]);  pa.u[3] = pk2(p[6], p[7]);
            pb.u[0] = pk2(p[8], p[9]);  pb.u[1] = pk2(p[10], p[11]);
            pb.u[2] = pk2(p[12], p[13]); pb.u[3] = pk2(p[14], p[15]);
            pfr[kb2][0] = pa.v;
            pfr[kb2][1] = pb.v;
        }
        l_own += lsum;

        // ---- PV: 16 mfma_32x32x16, O^T[dv][q] ----
        __builtin_amdgcn_s_setprio(1);
        #pragma unroll
        for (int kb2 = 0; kb2 < 4; ++kb2) {
            const int sub = kb2 >> 1;
            #pragma unroll
            for (int kkb = 0; kkb < 2; ++kkb) {
                const int m = (kb2 & 1) * 2 + kkb;
                const int slot = ((2 * m + hh) ^ (lq & 7)) << 3;
                bf16x8 v0 = *(const bf16x8*)&Vt[cur][sub][lq * 64 + slot];
                bf16x8 v1 = *(const bf16x8*)&Vt[cur][sub][(32 + lq) * 64 + slot];
                o0 = __builtin_amdgcn_mfma_f32_32x32x16_bf16(v0, pfr[kb2][kkb], o0, 0, 0, 0);
                o1 = __builtin_amdgcn_mfma_f32_32x32x16_bf16(v1, pfr[kb2][kkb], o1, 0, 0, 0);
            }
        }
        __builtin_amdgcn_s_setprio(0);

        __builtin_amdgcn_sched_barrier(0);
        __builtin_amdgcn_s_barrier();   // reads done before buf reuse
    }

    // ---- epilogue: l across the two lane halves, normalize, store O^T ----
    float l = l_own + __shfl_xor(l_own, 32, 64);
    float inv = __builtin_amdgcn_rcpf(l);
    float* fout = out + ((size_t)b * LL + qbase + lq) * DM + hd * DH + 4 * hh;
    #pragma unroll
    for (int rg = 0; rg < 4; ++rg) {
        float4 v0, v1;
        v0.x = o0[4 * rg + 0] * inv; v0.y = o0[4 * rg + 1] * inv;
        v0.z = o0[4 * rg + 2] * inv; v0.w = o0[4 * rg + 3] * inv;
        v1.x = o1[4 * rg + 0] * inv; v1.y = o1[4 * rg + 1] * inv;
        v1.z = o1[4 * rg + 2] * inv; v1.w = o1[4 * rg + 3] * inv;
        *(float4*)(fout + 8 * rg) = v0;
        *(float4*)(fout + 32 + 8 * rg) = v1;
    }
}

extern "C" void kernel_launch(void* const* d_in, const int* in_sizes, int n_in,
                              void* d_out, int out_size, void* d_ws, size_t ws_size,
                              hipStream_t stream) {
    const float* Q = (const float*)d_in[0];
    const float* K = (const float*)d_in[1];
    const float* V = (const float*)d_in[2];
    const void* mask = d_in[3];
    float* out = (float*)d_out;

    unsigned* bits = (unsigned*)d_ws;                           // 1 MB
    const size_t MASK_B = (size_t)2 * 16 * 2048 * 4 * 4;        // 1048576
    const size_t KV_B = (size_t)2 * NH * 32 * 4096 * 2;         // 8 MB each
    short* Kb = (short*)((char*)d_ws + MASK_B);
    short* Vb = (short*)((char*)d_ws + MASK_B + KV_B);

    pack_mask4<<<dim3(2 * 16 * 2048 * 4 / 256), dim3(256), 0, stream>>>(mask, bits);
    prep_k<<<dim3(32, NH, 2), dim3(256), 0, stream>>>(K, Kb);
    prep_v<<<dim3(32, NH, 2), dim3(256), 0, stream>>>(V, Vb);
    mha_fwd3<<<dim3(512), dim3(256), 0, stream>>>(Q, Kb, Vb, bits, out);
}